// Round 1
// baseline (672.936 us; speedup 1.0000x reference)
//
#include <hip/hip_runtime.h>
#include <math.h>

// Problem constants (from reference)
constexpr int BS = 16384;
constexpr int NC = 8192;
constexpr int THREADS = 256;
constexpr int V4PT = NC / (THREADS * 4);   // 8 float4 per thread (32 floats)

using f4 = __attribute__((ext_vector_type(4))) float;

// ---------------------------------------------------------------------------
// Pass 1: one block per row. Barrier-free streaming form:
//   - x[target] fetched via uniform scalar load (off the streaming path)
//   - whole row loaded into registers with PLAIN float4 loads (the verified
//     6.3 TB/s path; NT removed)
//   - thread-LOCAL max only (no barrier between load and exp pass)
//   - single fused pass: se (exp2-domain, local-max-shifted), sum x*lat, sum lat
//   - one cross-lane online-softmax merge + one LDS merge + one barrier total
// ---------------------------------------------------------------------------
__launch_bounds__(THREADS)
__global__ void self_filter_row_kernel(const float* __restrict__ x,
                                       const int* __restrict__ tgt,
                                       float* __restrict__ partial) {
    const int row  = blockIdx.x;
    const int t    = threadIdx.x;
    const int wave = t >> 6;
    const int lane = t & 63;

    const f4* rowp = reinterpret_cast<const f4*>(x + (size_t)row * NC);
    const int   tr = tgt[row];                    // uniform -> s_load
    const float xt = x[(size_t)row * NC + tr];    // uniform -> s_load

    __shared__ float s_my[4], s_se[4], s_xl[4], s_l[4];

    // ---- Load entire row into registers (single HBM pass, plain loads)
    f4 v[V4PT];
#pragma unroll
    for (int i = 0; i < V4PT; ++i)
        v[i] = rowp[i * THREADS + t];             // coalesced: wave reads 1 KiB/inst

    // ---- Thread-local max (no cross-thread sync needed before exp)
    float mx = -INFINITY;
#pragma unroll
    for (int i = 0; i < V4PT; ++i)
        mx = fmaxf(mx, fmaxf(fmaxf(v[i][0], v[i][1]), fmaxf(v[i][2], v[i][3])));

    const float L  = 1.4426950408889634f;         // log2(e)
    float my = mx * L;                            // thread-local max, exp2 domain
    const float yt = xt * L;

    // ---- Single fused pass over registers
    float se = 0.0f, sxl = 0.0f, sl = 0.0f;
#pragma unroll
    for (int i = 0; i < V4PT; ++i) {
#pragma unroll
        for (int k = 0; k < 4; ++k) {
            const float xv = v[i][k];
            const float y  = xv * L;
            se += __builtin_amdgcn_exp2f(y - my);           // exp(xv - mx_local)
            const float e2 = __builtin_amdgcn_exp2f(y - yt); // exp(xv - xt); ovf->inf->lat=0 (safe)
            const float conf = 0.2f - e2;
            const float lat  = conf > 0.0f ? conf : 0.0f;
            sxl = fmaf(xv, lat, sxl);
            sl += lat;
        }
    }

    // ---- Cross-lane butterfly: online-softmax merge for (my,se); plain sums
#pragma unroll
    for (int off = 32; off > 0; off >>= 1) {
        const float my2 = __shfl_xor(my, off, 64);
        const float se2 = __shfl_xor(se, off, 64);
        const float mn  = fmaxf(my, my2);
        se = se  * __builtin_amdgcn_exp2f(my  - mn)
           + se2 * __builtin_amdgcn_exp2f(my2 - mn);
        my = mn;
        sxl += __shfl_xor(sxl, off, 64);
        sl  += __shfl_xor(sl,  off, 64);
    }
    if (lane == 0) { s_my[wave] = my; s_se[wave] = se; s_xl[wave] = sxl; s_l[wave] = sl; }
    __syncthreads();                              // the ONLY barrier

    if (t == 0) {
        const float M = fmaxf(fmaxf(s_my[0], s_my[1]), fmaxf(s_my[2], s_my[3]));
        float S = 0.0f, XL = 0.0f, SL = 0.0f;
#pragma unroll
        for (int w = 0; w < 4; ++w) {
            S  += s_se[w] * __builtin_amdgcn_exp2f(s_my[w] - M);
            XL += s_xl[w];
            SL += s_l[w];
        }
        const float LN2 = 0.69314718055994531f;
        const float off_  = LN2 * (M + __builtin_amdgcn_logf(S)); // log-sum-exp (natural)
        const float total = XL - off_ * SL;       // sum_j log_prob_j * latent_j
        const float lp_t  = xt - off_;
        partial[row] = -lp_t - (0.1f / (float)(NC - 1)) * total;
    }
}

// ---------------------------------------------------------------------------
// Pass 2: one block sums the 16384 per-row partials and writes the scalar.
// (d_out is poisoned by the harness — we fully overwrite it.)
// ---------------------------------------------------------------------------
__launch_bounds__(THREADS)
__global__ void self_filter_reduce_kernel(const float* __restrict__ partial,
                                          float* __restrict__ out) {
    const int t    = threadIdx.x;
    const int wave = t >> 6;
    const int lane = t & 63;
    __shared__ float s_s[4];

    const f4* p4 = reinterpret_cast<const f4*>(partial);
    float s = 0.0f;
#pragma unroll
    for (int i = 0; i < BS / (THREADS * 4); ++i) {   // 16 float4 per thread
        const f4 v = p4[i * THREADS + t];
        s += (v[0] + v[1]) + (v[2] + v[3]);
    }
#pragma unroll
    for (int off = 32; off > 0; off >>= 1)
        s += __shfl_xor(s, off, 64);
    if (lane == 0) s_s[wave] = s;
    __syncthreads();
    if (t == 0)
        out[0] = (s_s[0] + s_s[1] + s_s[2] + s_s[3]) * (1.0f / (float)BS);
}

extern "C" void kernel_launch(void* const* d_in, const int* in_sizes, int n_in,
                              void* d_out, int out_size, void* d_ws, size_t ws_size,
                              hipStream_t stream) {
    const float* x   = (const float*)d_in[0];
    const int*   tgt = (const int*)d_in[1];
    float*       out = (float*)d_out;
    float*       partial = (float*)d_ws;          // 64 KiB of scratch

    self_filter_row_kernel<<<BS, THREADS, 0, stream>>>(x, tgt, partial);
    self_filter_reduce_kernel<<<1, THREADS, 0, stream>>>(partial, out);
}

// Round 3
// 644.600 us; speedup vs baseline: 1.0440x; 1.0440x over previous
//
#include <hip/hip_runtime.h>
#include <math.h>

// Problem constants (from reference)
constexpr int BS = 16384;
constexpr int NC = 8192;
constexpr int THREADS = 256;

constexpr int CHUNK_F4 = 8;                          // float4 per lane per chunk
constexpr int F4_PER_ROW = NC / 4;                   // 2048
constexpr int NCHUNK = F4_PER_ROW / (64 * CHUNK_F4); // 4 chunks per row

using f4 = __attribute__((ext_vector_type(4))) float;

__device__ __forceinline__ float ex2(float a) { return __builtin_amdgcn_exp2f(a); }

// ---------------------------------------------------------------------------
// Pass 1: one WAVE per row (4 rows per 256-thread block). Design goals:
//   - zero __syncthreads / zero LDS  -> no compiler-forced s_waitcnt vmcnt(0)
//     drains anywhere; loads stay in flight across the entire kernel
//   - ping-pong register chunks (8 float4/lane) with next-chunk NT loads
//     issued BEFORE computing the current chunk (1-deep software pipeline,
//     all indices static -> stays in VGPRs)
//   - nontemporal loads (read-once 512 MiB stream; don't write-allocate L2/L3)
//   - ONE transcendental per element: e = exp2(y - my); p_j/p_t = e * Kc
//     with per-chunk Kc = exp2(my - yt)
//   - online-softmax (my, se) maintained per lane, merged across lanes with a
//     6-step shfl_xor butterfly at the end
// ---------------------------------------------------------------------------
__launch_bounds__(THREADS, 4)
__global__ void self_filter_row_kernel(const float* __restrict__ x,
                                       const int* __restrict__ tgt,
                                       float* __restrict__ partial) {
    const int t    = threadIdx.x;
    const int wave = t >> 6;
    const int lane = t & 63;
    const int row  = (blockIdx.x << 2) | wave;       // grid = BS/4 blocks

    const f4* rowp = reinterpret_cast<const f4*>(x + (size_t)row * NC);
    const int   tr = tgt[row];                       // wave-uniform
    const float xt = x[(size_t)row * NC + tr];       // wave-uniform scalar

    const float L  = 1.4426950408889634f;            // log2(e)
    const float yt = xt * L;

    float my = -INFINITY;                            // running max (exp2 domain)
    float se = 0.0f, sxl = 0.0f, sl = 0.0f;

    f4 A[CHUNK_F4], B[CHUNK_F4];

#define LOADC(buf, c)                                                       \
    _Pragma("unroll")                                                       \
    for (int i = 0; i < CHUNK_F4; ++i)                                      \
        buf[i] = __builtin_nontemporal_load(                                \
            &rowp[(c) * (64 * CHUNK_F4) + i * 64 + lane]);

#define PROCC(buf)                                                          \
    {                                                                       \
        float cm = -INFINITY;                                               \
        _Pragma("unroll")                                                   \
        for (int i = 0; i < CHUNK_F4; ++i)                                  \
            cm = fmaxf(cm, fmaxf(fmaxf(buf[i][0], buf[i][1]),               \
                                 fmaxf(buf[i][2], buf[i][3])));             \
        const float mn = fmaxf(my, cm * L);                                 \
        se *= ex2(my - mn);           /* rescale old sum; first chunk: 0 */ \
        my = mn;                                                            \
        const float Kc = ex2(my - yt);                                      \
        _Pragma("unroll")                                                   \
        for (int i = 0; i < CHUNK_F4; ++i) {                                \
            _Pragma("unroll")                                               \
            for (int k = 0; k < 4; ++k) {                                   \
                const float xv = buf[i][k];                                 \
                const float e  = ex2(fmaf(xv, L, -my)); /* exp(xv-mx) */    \
                se += e;                                                    \
                const float conf = fmaf(e, -Kc, 0.2f);  /* 0.2 - p/pt */    \
                const float lat  = fmaxf(conf, 0.0f);                       \
                sxl = fmaf(xv, lat, sxl);                                   \
                sl += lat;                                                  \
            }                                                               \
        }                                                                   \
    }

    // ---- 1-deep software-pipelined chunk stream (4 chunks, static ping-pong)
    LOADC(A, 0);
    LOADC(B, 1);
    PROCC(A);          // B's loads in flight under A's compute
    LOADC(A, 2);
    PROCC(B);          // A(c2) in flight
    LOADC(B, 3);
    PROCC(A);          // B(c3) in flight
    PROCC(B);

#undef LOADC
#undef PROCC

    // ---- Cross-lane butterfly: online-softmax merge for (my,se); plain sums
#pragma unroll
    for (int off = 32; off > 0; off >>= 1) {
        const float my2 = __shfl_xor(my, off, 64);
        const float se2 = __shfl_xor(se, off, 64);
        const float mn  = fmaxf(my, my2);
        se = se * ex2(my - mn) + se2 * ex2(my2 - mn);
        my = mn;
        sxl += __shfl_xor(sxl, off, 64);
        sl  += __shfl_xor(sl,  off, 64);
    }

    if (lane == 0) {
        const float LN2  = 0.69314718055994531f;
        const float off_ = LN2 * (my + __builtin_amdgcn_logf(se)); // m + ln(S)
        const float total = sxl - off_ * sl;    // sum_j log_prob_j * latent_j
        const float lp_t  = xt - off_;
        partial[row] = -lp_t - (0.1f / (float)(NC - 1)) * total;
    }
}

// ---------------------------------------------------------------------------
// Pass 2: one block sums the 16384 per-row partials and writes the scalar.
// (d_out is poisoned by the harness — we fully overwrite it.)
// ---------------------------------------------------------------------------
__launch_bounds__(THREADS)
__global__ void self_filter_reduce_kernel(const float* __restrict__ partial,
                                          float* __restrict__ out) {
    const int t    = threadIdx.x;
    const int wave = t >> 6;
    const int lane = t & 63;
    __shared__ float s_s[4];

    const f4* p4 = reinterpret_cast<const f4*>(partial);
    float s = 0.0f;
#pragma unroll
    for (int i = 0; i < BS / (THREADS * 4); ++i) {   // 16 float4 per thread
        const f4 v = p4[i * THREADS + t];
        s += (v[0] + v[1]) + (v[2] + v[3]);
    }
#pragma unroll
    for (int off = 32; off > 0; off >>= 1)
        s += __shfl_xor(s, off, 64);
    if (lane == 0) s_s[wave] = s;
    __syncthreads();
    if (t == 0)
        out[0] = (s_s[0] + s_s[1] + s_s[2] + s_s[3]) * (1.0f / (float)BS);
}

extern "C" void kernel_launch(void* const* d_in, const int* in_sizes, int n_in,
                              void* d_out, int out_size, void* d_ws, size_t ws_size,
                              hipStream_t stream) {
    const float* x   = (const float*)d_in[0];
    const int*   tgt = (const int*)d_in[1];
    float*       out = (float*)d_out;
    float*       partial = (float*)d_ws;          // 64 KiB of scratch

    self_filter_row_kernel<<<BS / 4, THREADS, 0, stream>>>(x, tgt, partial);
    self_filter_reduce_kernel<<<1, THREADS, 0, stream>>>(partial, out);
}